// Round 9
// baseline (251.198 us; speedup 1.0000x reference)
//
#include <hip/hip_runtime.h>
#include <math.h>

// Problem constants
#define BATCH 256
#define IC    1152
#define EDIM  8
#define NC    10
#define DV    16

#define ITB   16                 // i's per B-block
#define NSLAB (IC / ITB)         // 72 partial slabs
#define CDB   (NC * DV * BATCH)  // 40960 floats per slab

// ---------------------------------------------------------------------------
// dot8: u = W[i,c,d,:] . x[b,i,:]  (w wave-uniform -> SGPR operands)
// ---------------------------------------------------------------------------
__device__ __forceinline__ float dot8(const float* __restrict__ w,
                                      float4 a, float4 b) {
    float u = w[0] * a.x;
    u = fmaf(w[1], a.y, u);
    u = fmaf(w[2], a.z, u);
    u = fmaf(w[3], a.w, u);
    u = fmaf(w[4], b.x, u);
    u = fmaf(w[5], b.y, u);
    u = fmaf(w[6], b.z, u);
    u = fmaf(w[7], b.w, u);
    return u;
}

// ---------------------------------------------------------------------------
// Kernel A: routing coefficients. Grid = 1152 (one i per block), block = 256
// threads = 256 batch elements (lane = b). i, c, d are wave-uniform -> W loads
// scalarize to s_load; agreement sum over d is a thread-local FMA chain;
// softmax over the 10 c's is thread-local. ZERO cross-lane ops, ZERO LDS.
//   MODE 2: logits = (u.v1) + 2*bias          -> cw
//   MODE 3: logits = (u.v2) + (u.v1) + 3*bias -> cw   (b2 never materialized)
// vT layout: vT[(c*16+d)*256 + b]  (coalesced across lanes).
// cw layout: cw[(i*10+c)*256 + b].
// ---------------------------------------------------------------------------
template<int MODE>
__global__ __launch_bounds__(256)
void caps_cw(const float* __restrict__ x,
             const float* __restrict__ W,
             const float* __restrict__ bias,
             const float* __restrict__ vT1,
             const float* __restrict__ vT2,
             float* __restrict__ cw_g)
{
    const int i = blockIdx.x;
    const int b = threadIdx.x;

    const float4 xv0 = ((const float4*)x)[((size_t)b * IC + i) * 2 + 0];
    const float4 xv1 = ((const float4*)x)[((size_t)b * IC + i) * 2 + 1];
    const float* Wi = W + (size_t)i * NC * DV * EDIM;

    float t2[NC];          // agreement vs v1
    float t3[NC];          // agreement vs v2 (MODE 3 only)

    #pragma unroll
    for (int c = 0; c < NC; ++c) {
        const float* Wc = Wi + c * DV * EDIM;
        float a2 = 0.f, a3 = 0.f;
        #pragma unroll
        for (int d = 0; d < DV; ++d) {
            float u = dot8(Wc + d * EDIM, xv0, xv1);
            a2 = fmaf(u, vT1[(c * DV + d) * BATCH + b], a2);
            if (MODE == 3)
                a3 = fmaf(u, vT2[(c * DV + d) * BATCH + b], a3);
        }
        t2[c] = a2;
        if (MODE == 3) t3[c] = a3;
    }

    // thread-local softmax (no max-subtraction: logits bounded << 88)
    float ex[NC];
    float ssum = 0.f;
    #pragma unroll
    for (int c = 0; c < NC; ++c) {
        float bv = bias[i * NC + c];
        float logit = (MODE == 2) ? (t2[c] + 2.0f * bv)
                                  : (t3[c] + t2[c] + 3.0f * bv);
        ex[c] = __expf(logit);
        ssum += ex[c];
    }
    float inv = 1.0f / ssum;
    #pragma unroll
    for (int c = 0; c < NC; ++c)
        cw_g[((size_t)i * NC + c) * BATCH + b] = ex[c] * inv;
}

// ---------------------------------------------------------------------------
// Kernel B: weighted sum. Grid = (72 icb, 10 c, 2 dh), block = 256 (lane = b).
// Each block: fixed (c, d-half), loops 16 i's, accumulates s[8] in registers,
// writes one slab row. W wave-uniform -> scalar pipe. No cross-lane, no LDS.
// FIRST=1: cw = softmax(bias[i,:]) computed in-thread (uniform), cw_g unused.
// ---------------------------------------------------------------------------
template<int FIRST>
__global__ __launch_bounds__(256)
void caps_wsum(const float* __restrict__ x,
               const float* __restrict__ W,
               const float* __restrict__ bias,
               const float* __restrict__ cw_g,
               float* __restrict__ slab)
{
    const int icb = blockIdx.x;
    const int c   = blockIdx.y;
    const int dh  = blockIdx.z;
    const int b   = threadIdx.x;
    const int i0  = icb * ITB;

    float s[8];
    #pragma unroll
    for (int q = 0; q < 8; ++q) s[q] = 0.f;

    #pragma unroll 1
    for (int ii = 0; ii < ITB; ++ii) {
        const int i = i0 + ii;
        const float4 xv0 = ((const float4*)x)[((size_t)b * IC + i) * 2 + 0];
        const float4 xv1 = ((const float4*)x)[((size_t)b * IC + i) * 2 + 1];

        float cw;
        if (FIRST) {
            // softmax(bias[i,:]) — wave-uniform
            float ssum = 0.f, ec = 0.f;
            #pragma unroll
            for (int cc = 0; cc < NC; ++cc) {
                float e = __expf(bias[i * NC + cc]);
                ssum += e;
                if (cc == c) ec = e;
            }
            cw = ec / ssum;
        } else {
            cw = cw_g[((size_t)i * NC + c) * BATCH + b];
        }

        const float* wb = W + (((size_t)i * NC + c) * DV + dh * 8) * EDIM;
        #pragma unroll
        for (int q = 0; q < 8; ++q) {
            float u = dot8(wb + q * EDIM, xv0, xv1);
            s[q] = fmaf(cw, u, s[q]);
        }
    }

    #pragma unroll
    for (int q = 0; q < 8; ++q)
        slab[(size_t)icb * CDB + (c * DV + dh * 8 + q) * BATCH + b] = s[q];
}

// ---------------------------------------------------------------------------
// Squash: reduce 72 slabs, apply squash. Grid = (10 c, 16 bgrp), block = 256:
// d = tid>>4, bs = tid&15 (b contiguous in low lanes -> coalesced loads).
// d-reduction via small LDS transpose tile. LAST=0 -> write vT layout;
// LAST=1 -> write final out[b][c][d].
// ---------------------------------------------------------------------------
template<int LAST>
__global__ __launch_bounds__(256)
void caps_squash(const float* __restrict__ slab, float* __restrict__ outp)
{
    __shared__ float tile[DV][17];
    const int c  = blockIdx.x;
    const int bg = blockIdx.y;
    const int d  = threadIdx.x >> 4;
    const int bs = threadIdx.x & 15;
    const int b  = bg * 16 + bs;

    float a[4] = {0.f, 0.f, 0.f, 0.f};
    #pragma unroll
    for (int s0 = 0; s0 < NSLAB; s0 += 4) {
        #pragma unroll
        for (int j = 0; j < 4; ++j)
            a[j] += slab[(size_t)(s0 + j) * CDB + (c * DV + d) * BATCH + b];
    }
    float s = (a[0] + a[1]) + (a[2] + a[3]);

    tile[d][bs] = s;
    __syncthreads();
    float sq = 0.f;
    #pragma unroll
    for (int k = 0; k < DV; ++k) {
        float v = tile[k][bs];
        sq = fmaf(v, v, sq);
    }

    // scale = sq/(1+sq)/sqrt(sq+EPS), EPS = 1e-7 (matches reference)
    float scale = sq / ((1.0f + sq) * sqrtf(sq + 1e-7f));
    float val = scale * s;

    if (LAST)
        outp[((size_t)b * NC + c) * DV + d] = val;      // out[b][c][d]
    else
        outp[(c * DV + d) * BATCH + b] = val;           // vT[c][d][b]
}

// ---------------------------------------------------------------------------
extern "C" void kernel_launch(void* const* d_in, const int* in_sizes, int n_in,
                              void* d_out, int out_size, void* d_ws, size_t ws_size,
                              hipStream_t stream)
{
    const float* x    = (const float*)d_in[0];   // [256,1152,8]
    const float* W    = (const float*)d_in[1];   // [1152,10,16,8]
    const float* bias = (const float*)d_in[2];   // [1152,10]
    float* out = (float*)d_out;                  // [256,10,16]

    float* ws   = (float*)d_ws;
    float* slab = ws;                            // 72*40960   = 2,949,120 f
    float* cw_g = slab + (size_t)NSLAB * CDB;    //              2,949,120 f
    float* vT1  = cw_g + (size_t)IC * NC * BATCH;//                 40,960 f
    float* vT2  = vT1 + CDB / 1 * 0 + (NC * DV * BATCH); //         40,960 f
    // total ws use: ~23.9 MB (< 35.5 MB proven)

    dim3 gB(NSLAB, NC, 2);   // 1440 blocks
    dim3 gS(NC, 16);         // 160 blocks

    // iter 1: cw = softmax(bias) (in-kernel), weighted sum, squash -> vT1
    caps_wsum<1><<<gB, 256, 0, stream>>>(x, W, bias, cw_g, slab);
    caps_squash<0><<<gS, 256, 0, stream>>>(slab, vT1);
    // iter 2: cw from agr(v1), weighted sum, squash -> vT2
    caps_cw<2><<<IC, 256, 0, stream>>>(x, W, bias, vT1, vT1, cw_g);
    caps_wsum<0><<<gB, 256, 0, stream>>>(x, W, bias, cw_g, slab);
    caps_squash<0><<<gS, 256, 0, stream>>>(slab, vT2);
    // iter 3: cw from agr(v2)+agr(v1)+3*bias, weighted sum, squash -> out
    caps_cw<3><<<IC, 256, 0, stream>>>(x, W, bias, vT1, vT2, cw_g);
    caps_wsum<0><<<gB, 256, 0, stream>>>(x, W, bias, cw_g, slab);
    caps_squash<1><<<gS, 256, 0, stream>>>(slab, out);
}

// Round 10
// 208.856 us; speedup vs baseline: 1.2027x; 1.2027x over previous
//
#include <hip/hip_runtime.h>
#include <math.h>

// Problem constants
#define BATCH 256
#define IC    1152
#define EDIM  8
#define NC    10
#define DV    16

#define ITB   16                 // i's per B-block
#define NSLAB (IC / ITB)         // 72 partial slabs
#define CDB   (NC * DV * BATCH)  // 40960 floats per slab

// ---------------------------------------------------------------------------
// dot8: u = W[i,c,d,:] . x[b,i,:]  (w wave-uniform -> SGPR operands)
// ---------------------------------------------------------------------------
__device__ __forceinline__ float dot8(const float* __restrict__ w,
                                      float4 a, float4 b) {
    float u = w[0] * a.x;
    u = fmaf(w[1], a.y, u);
    u = fmaf(w[2], a.z, u);
    u = fmaf(w[3], a.w, u);
    u = fmaf(w[4], b.x, u);
    u = fmaf(w[5], b.y, u);
    u = fmaf(w[6], b.z, u);
    u = fmaf(w[7], b.w, u);
    return u;
}

// ---------------------------------------------------------------------------
// x transpose: x[b][i][e] -> xT[i][b][e]. R9's lane=b kernels read x with a
// 36 KB inter-lane stride (64 line-requests per load). One LDS-tiled
// transpose makes every downstream x access a contiguous 1 KB/wave dwordx4.
// Tile 16b x 16i; pad row stride to 132 floats (2-way banks, free).
// ---------------------------------------------------------------------------
__global__ __launch_bounds__(256)
void caps_xT(const float* __restrict__ x, float* __restrict__ xT)
{
    __shared__ float tile[16][132];
    const int t  = threadIdx.x;
    const int i0 = blockIdx.x * 16;
    const int b0 = blockIdx.y * 16;
    {
        const int b = t >> 4, i = t & 15;    // lanes vary i: 32B stride reads
        const float4* src = (const float4*)&x[((size_t)(b0 + b) * IC + i0 + i) * EDIM];
        float4 v0 = src[0], v1 = src[1];
        ((float4*)&tile[b][i * 8])[0] = v0;
        ((float4*)&tile[b][i * 8])[1] = v1;
    }
    __syncthreads();
    {
        const int i = t >> 4, b = t & 15;    // lanes vary b: contiguous writes
        float4 v0 = ((const float4*)&tile[b][i * 8])[0];
        float4 v1 = ((const float4*)&tile[b][i * 8])[1];
        float4* dst = (float4*)&xT[((size_t)(i0 + i) * BATCH + b0 + b) * EDIM];
        dst[0] = v0;
        dst[1] = v1;
    }
}

// ---------------------------------------------------------------------------
// Kernel A: routing coefficients. Grid = 1152 (one i per block), block = 256
// threads = 256 batch elements (lane = b). i, c, d are wave-uniform -> W loads
// scalarize to s_load; agreement sum over d is a thread-local FMA chain;
// softmax over the 10 c's is thread-local. ZERO cross-lane ops, ZERO LDS.
//   MODE 2: logits = (u.v1) + 2*bias          -> cw
//   MODE 3: logits = (u.v2) + (u.v1) + 3*bias -> cw   (b2 never materialized)
// vT layout: vT[(c*16+d)*256 + b]; cw layout: cw[(i*10+c)*256 + b].
// ---------------------------------------------------------------------------
template<int MODE>
__global__ __launch_bounds__(256)
void caps_cw(const float* __restrict__ xT,
             const float* __restrict__ W,
             const float* __restrict__ bias,
             const float* __restrict__ vT1,
             const float* __restrict__ vT2,
             float* __restrict__ cw_g)
{
    const int i = blockIdx.x;
    const int b = threadIdx.x;

    const float4 xv0 = ((const float4*)xT)[((size_t)i * BATCH + b) * 2 + 0];
    const float4 xv1 = ((const float4*)xT)[((size_t)i * BATCH + b) * 2 + 1];
    const float* Wi = W + (size_t)i * NC * DV * EDIM;

    float t2[NC];          // agreement vs v1
    float t3[NC];          // agreement vs v2 (MODE 3 only)

    #pragma unroll
    for (int c = 0; c < NC; ++c) {
        const float* Wc = Wi + c * DV * EDIM;
        float a2 = 0.f, a3 = 0.f;
        #pragma unroll
        for (int d = 0; d < DV; ++d) {
            float u = dot8(Wc + d * EDIM, xv0, xv1);
            a2 = fmaf(u, vT1[(c * DV + d) * BATCH + b], a2);
            if (MODE == 3)
                a3 = fmaf(u, vT2[(c * DV + d) * BATCH + b], a3);
        }
        t2[c] = a2;
        if (MODE == 3) t3[c] = a3;
    }

    // thread-local softmax (no max-subtraction: logits bounded << 88)
    float ex[NC];
    float ssum = 0.f;
    #pragma unroll
    for (int c = 0; c < NC; ++c) {
        float bv = bias[i * NC + c];
        float logit = (MODE == 2) ? (t2[c] + 2.0f * bv)
                                  : (t3[c] + t2[c] + 3.0f * bv);
        ex[c] = __expf(logit);
        ssum += ex[c];
    }
    float inv = 1.0f / ssum;
    #pragma unroll
    for (int c = 0; c < NC; ++c)
        cw_g[((size_t)i * NC + c) * BATCH + b] = ex[c] * inv;
}

// ---------------------------------------------------------------------------
// Kernel B: weighted sum. Grid = (72 icb, 10 c, 2 dh), block = 256 (lane = b).
// Each block: fixed (c, d-half), loops 16 i's, accumulates s[8] in registers,
// writes one slab row. W wave-uniform -> scalar pipe. No cross-lane, no LDS.
// FIRST=1: cw = softmax(bias[i,:]) computed in-thread (uniform), cw_g unused.
// ---------------------------------------------------------------------------
template<int FIRST>
__global__ __launch_bounds__(256)
void caps_wsum(const float* __restrict__ xT,
               const float* __restrict__ W,
               const float* __restrict__ bias,
               const float* __restrict__ cw_g,
               float* __restrict__ slab)
{
    const int icb = blockIdx.x;
    const int c   = blockIdx.y;
    const int dh  = blockIdx.z;
    const int b   = threadIdx.x;
    const int i0  = icb * ITB;

    float s[8];
    #pragma unroll
    for (int q = 0; q < 8; ++q) s[q] = 0.f;

    #pragma unroll 1
    for (int ii = 0; ii < ITB; ++ii) {
        const int i = i0 + ii;
        const float4 xv0 = ((const float4*)xT)[((size_t)i * BATCH + b) * 2 + 0];
        const float4 xv1 = ((const float4*)xT)[((size_t)i * BATCH + b) * 2 + 1];

        float cw;
        if (FIRST) {
            // softmax(bias[i,:]) — wave-uniform
            float ssum = 0.f, ec = 0.f;
            #pragma unroll
            for (int cc = 0; cc < NC; ++cc) {
                float e = __expf(bias[i * NC + cc]);
                ssum += e;
                if (cc == c) ec = e;
            }
            cw = ec / ssum;
        } else {
            cw = cw_g[((size_t)i * NC + c) * BATCH + b];
        }

        const float* wb = W + (((size_t)i * NC + c) * DV + dh * 8) * EDIM;
        #pragma unroll
        for (int q = 0; q < 8; ++q) {
            float u = dot8(wb + q * EDIM, xv0, xv1);
            s[q] = fmaf(cw, u, s[q]);
        }
    }

    #pragma unroll
    for (int q = 0; q < 8; ++q)
        slab[(size_t)icb * CDB + (c * DV + dh * 8 + q) * BATCH + b] = s[q];
}

// ---------------------------------------------------------------------------
// Squash: reduce 72 slabs, apply squash. Grid = (10 c, 16 bgrp), block = 256:
// d = tid>>4, bs = tid&15 (b contiguous in low lanes -> coalesced loads).
// d-reduction via small LDS transpose tile. LAST=0 -> write vT layout;
// LAST=1 -> write final out[b][c][d].
// ---------------------------------------------------------------------------
template<int LAST>
__global__ __launch_bounds__(256)
void caps_squash(const float* __restrict__ slab, float* __restrict__ outp)
{
    __shared__ float tile[DV][17];
    const int c  = blockIdx.x;
    const int bg = blockIdx.y;
    const int d  = threadIdx.x >> 4;
    const int bs = threadIdx.x & 15;
    const int b  = bg * 16 + bs;

    float a[4] = {0.f, 0.f, 0.f, 0.f};
    #pragma unroll
    for (int s0 = 0; s0 < NSLAB; s0 += 4) {
        #pragma unroll
        for (int j = 0; j < 4; ++j)
            a[j] += slab[(size_t)(s0 + j) * CDB + (c * DV + d) * BATCH + b];
    }
    float s = (a[0] + a[1]) + (a[2] + a[3]);

    tile[d][bs] = s;
    __syncthreads();
    float sq = 0.f;
    #pragma unroll
    for (int k = 0; k < DV; ++k) {
        float v = tile[k][bs];
        sq = fmaf(v, v, sq);
    }

    // scale = sq/(1+sq)/sqrt(sq+EPS), EPS = 1e-7 (matches reference)
    float scale = sq / ((1.0f + sq) * sqrtf(sq + 1e-7f));
    float val = scale * s;

    if (LAST)
        outp[((size_t)b * NC + c) * DV + d] = val;      // out[b][c][d]
    else
        outp[(c * DV + d) * BATCH + b] = val;           // vT[c][d][b]
}

// ---------------------------------------------------------------------------
extern "C" void kernel_launch(void* const* d_in, const int* in_sizes, int n_in,
                              void* d_out, int out_size, void* d_ws, size_t ws_size,
                              hipStream_t stream)
{
    const float* x    = (const float*)d_in[0];   // [256,1152,8]
    const float* W    = (const float*)d_in[1];   // [1152,10,16,8]
    const float* bias = (const float*)d_in[2];   // [1152,10]
    float* out = (float*)d_out;                  // [256,10,16]

    float* ws   = (float*)d_ws;
    float* slab = ws;                                  // 2,949,120 f
    float* cw_g = slab + (size_t)NSLAB * CDB;          // 2,949,120 f
    float* vT1  = cw_g + (size_t)IC * NC * BATCH;      //    40,960 f
    float* vT2  = vT1 + NC * DV * BATCH;               //    40,960 f
    float* xT   = vT2 + NC * DV * BATCH;               // 2,359,296 f
    // total ws use: ~33.2 MB (< 35.5 MB proven)

    dim3 gT(IC / 16, BATCH / 16);  // 72 x 16 transpose blocks
    dim3 gB(NSLAB, NC, 2);         // 1440 blocks
    dim3 gS(NC, 16);               // 160 blocks

    // one-time x transpose (b-major -> i-major)
    caps_xT<<<gT, 256, 0, stream>>>(x, xT);
    // iter 1: cw = softmax(bias) (in-kernel), weighted sum, squash -> vT1
    caps_wsum<1><<<gB, 256, 0, stream>>>(xT, W, bias, cw_g, slab);
    caps_squash<0><<<gS, 256, 0, stream>>>(slab, vT1);
    // iter 2: cw from agr(v1), weighted sum, squash -> vT2
    caps_cw<2><<<IC, 256, 0, stream>>>(xT, W, bias, vT1, vT1, cw_g);
    caps_wsum<0><<<gB, 256, 0, stream>>>(xT, W, bias, cw_g, slab);
    caps_squash<0><<<gS, 256, 0, stream>>>(slab, vT2);
    // iter 3: cw from agr(v2)+agr(v1)+3*bias, weighted sum, squash -> out
    caps_cw<3><<<IC, 256, 0, stream>>>(xT, W, bias, vT1, vT2, cw_g);
    caps_wsum<0><<<gB, 256, 0, stream>>>(xT, W, bias, cw_g, slab);
    caps_squash<1><<<gS, 256, 0, stream>>>(slab, out);
}

// Round 11
// 193.673 us; speedup vs baseline: 1.2970x; 1.0784x over previous
//
#include <hip/hip_runtime.h>
#include <math.h>

// Problem constants
#define BATCH 256
#define IC    1152
#define EDIM  8
#define NC    10
#define DV    16

#define ITB   16                 // i's per B-block
#define NSLAB (IC / ITB)         // 72 partial slabs
#define CDB   (NC * DV * BATCH)  // 40960 floats per slab

// ---------------------------------------------------------------------------
// dot8 on LDS-resident weights (two float4 broadcast reads)
// ---------------------------------------------------------------------------
__device__ __forceinline__ float dot8w(float4 w0, float4 w1, float4 a, float4 b) {
    float u = w0.x * a.x;
    u = fmaf(w0.y, a.y, u);
    u = fmaf(w0.z, a.z, u);
    u = fmaf(w0.w, a.w, u);
    u = fmaf(w1.x, b.x, u);
    u = fmaf(w1.y, b.y, u);
    u = fmaf(w1.z, b.z, u);
    u = fmaf(w1.w, b.w, u);
    return u;
}

// ---------------------------------------------------------------------------
// x transpose: x[b][i][e] -> xT[i][b][e]  (+ one-time cw1 = softmax(bias))
// ---------------------------------------------------------------------------
__global__ __launch_bounds__(256)
void caps_xT(const float* __restrict__ x, const float* __restrict__ bias,
             float* __restrict__ xT, float* __restrict__ cw1)
{
    __shared__ float tile[16][132];
    const int t  = threadIdx.x;
    const int i0 = blockIdx.x * 16;
    const int b0 = blockIdx.y * 16;
    {
        const int b = t >> 4, i = t & 15;
        const float4* src = (const float4*)&x[((size_t)(b0 + b) * IC + i0 + i) * EDIM];
        float4 v0 = src[0], v1 = src[1];
        ((float4*)&tile[b][i * 8])[0] = v0;
        ((float4*)&tile[b][i * 8])[1] = v1;
    }
    // batch-independent first-iter routing weights: cw1[i,c] = softmax(bias[i,:])
    if (blockIdx.y == 0 && t < 16 * NC) {
        const int i = i0 + t / NC;
        const int c = t - (t / NC) * NC;
        float ssum = 0.f, ec = 0.f;
        #pragma unroll
        for (int cc = 0; cc < NC; ++cc) {
            float e = __expf(bias[i * NC + cc]);
            ssum += e;
            if (cc == c) ec = e;
        }
        cw1[i * NC + c] = ec / ssum;
    }
    __syncthreads();
    {
        const int i = t >> 4, b = t & 15;
        float4 v0 = ((const float4*)&tile[b][i * 8])[0];
        float4 v1 = ((const float4*)&tile[b][i * 8])[1];
        float4* dst = (float4*)&xT[((size_t)(i0 + i) * BATCH + b0 + b) * EDIM];
        dst[0] = v0;
        dst[1] = v1;
    }
}

// ---------------------------------------------------------------------------
// Kernel A: routing coefficients. Grid = 1152 (one i), block = 256 (lane = b).
// W[i] (5 KB) is staged to LDS with coalesced vector loads; dot8 reads it as
// uniform ds_read_b128 broadcasts. R10 let the compiler scalarize W ->
// ~160 serial s_load+lgkmcnt(0) round-trips per thread = the latency wall.
//   MODE 2: logits = (u.v1) + 2*bias          -> cw
//   MODE 3: logits = (u.v2) + (u.v1) + 3*bias -> cw   (b2 never materialized)
// ---------------------------------------------------------------------------
template<int MODE>
__global__ __launch_bounds__(256)
void caps_cw(const float* __restrict__ xT,
             const float* __restrict__ W,
             const float* __restrict__ bias,
             const float* __restrict__ vT1,
             const float* __restrict__ vT2,
             float* __restrict__ cw_g)
{
    __shared__ float4 sW[NC * DV * EDIM / 4];   // 320 float4 = 5 KB

    const int i = blockIdx.x;
    const int b = threadIdx.x;

    {   // cooperative W[i] stage (coalesced 16B loads)
        const float4* Wg = (const float4*)(W + (size_t)i * NC * DV * EDIM);
        #pragma unroll
        for (int f = b; f < NC * DV * EDIM / 4; f += 256)
            sW[f] = Wg[f];
    }

    const float4 xv0 = ((const float4*)xT)[((size_t)i * BATCH + b) * 2 + 0];
    const float4 xv1 = ((const float4*)xT)[((size_t)i * BATCH + b) * 2 + 1];

    __syncthreads();

    float t2[NC];
    float t3[NC];

    #pragma unroll
    for (int c = 0; c < NC; ++c) {
        float a2 = 0.f, a3 = 0.f;
        #pragma unroll
        for (int d = 0; d < DV; ++d) {
            float4 w0 = sW[(c * DV + d) * 2 + 0];
            float4 w1 = sW[(c * DV + d) * 2 + 1];
            float u = dot8w(w0, w1, xv0, xv1);
            a2 = fmaf(u, vT1[(c * DV + d) * BATCH + b], a2);
            if (MODE == 3)
                a3 = fmaf(u, vT2[(c * DV + d) * BATCH + b], a3);
        }
        t2[c] = a2;
        if (MODE == 3) t3[c] = a3;
    }

    // thread-local softmax (no max-subtraction: logits bounded << 88)
    float ex[NC];
    float ssum = 0.f;
    #pragma unroll
    for (int c = 0; c < NC; ++c) {
        float bv = bias[i * NC + c];
        float logit = (MODE == 2) ? (t2[c] + 2.0f * bv)
                                  : (t3[c] + t2[c] + 3.0f * bv);
        ex[c] = __expf(logit);
        ssum += ex[c];
    }
    float inv = 1.0f / ssum;
    #pragma unroll
    for (int c = 0; c < NC; ++c)
        cw_g[((size_t)i * NC + c) * BATCH + b] = ex[c] * inv;
}

// ---------------------------------------------------------------------------
// Kernel B: weighted sum. Grid = (72 icb, 10 c, 2 dh), block = 256 (lane = b).
// W tile (16 i x 8 d x 8 e = 4 KB) staged to LDS. ii-loop unrolled x4 so the
// xT/cw VMEM loads pipeline. FIRST=1 reads precomputed cw1[i,c].
// ---------------------------------------------------------------------------
template<int FIRST>
__global__ __launch_bounds__(256)
void caps_wsum(const float* __restrict__ xT,
               const float* __restrict__ W,
               const float* __restrict__ cw1,
               const float* __restrict__ cw_g,
               float* __restrict__ slab)
{
    __shared__ float4 sW[ITB * 16];   // [ii][16 float4] = 4 KB

    const int icb = blockIdx.x;
    const int c   = blockIdx.y;
    const int dh  = blockIdx.z;
    const int b   = threadIdx.x;
    const int i0  = icb * ITB;

    {   // cooperative W tile stage: row = ii (16 float4 per row), coalesced
        const int row = b >> 4, col = b & 15;
        sW[b] = ((const float4*)W)[((size_t)(i0 + row) * NC + c) * (DV * EDIM / 4)
                                   + dh * 16 + col];
    }

    float s[8];
    #pragma unroll
    for (int q = 0; q < 8; ++q) s[q] = 0.f;

    __syncthreads();

    #pragma unroll 4
    for (int ii = 0; ii < ITB; ++ii) {
        const int i = i0 + ii;
        const float4 xv0 = ((const float4*)xT)[((size_t)i * BATCH + b) * 2 + 0];
        const float4 xv1 = ((const float4*)xT)[((size_t)i * BATCH + b) * 2 + 1];

        const float cw = FIRST ? cw1[i * NC + c]
                               : cw_g[((size_t)i * NC + c) * BATCH + b];

        #pragma unroll
        for (int q = 0; q < 8; ++q) {
            float4 w0 = sW[ii * 16 + q * 2 + 0];
            float4 w1 = sW[ii * 16 + q * 2 + 1];
            float u = dot8w(w0, w1, xv0, xv1);
            s[q] = fmaf(cw, u, s[q]);
        }
    }

    #pragma unroll
    for (int q = 0; q < 8; ++q)
        slab[(size_t)icb * CDB + (c * DV + dh * 8 + q) * BATCH + b] = s[q];
}

// ---------------------------------------------------------------------------
// Squash: reduce 72 slabs + squash. Grid = (10 c, 16 bgrp), block = 1024:
// bs = tid&15, d = (tid>>4)&15, sg = tid>>8 (4 slab sub-groups of 18).
// LAST=0 -> vT[c][d][b]; LAST=1 -> out[b][c][d].
// ---------------------------------------------------------------------------
template<int LAST>
__global__ __launch_bounds__(1024)
void caps_squash(const float* __restrict__ slab, float* __restrict__ outp)
{
    __shared__ float part[4][DV][17];
    const int c  = blockIdx.x;
    const int bg = blockIdx.y;
    const int bs = threadIdx.x & 15;
    const int d  = (threadIdx.x >> 4) & 15;
    const int sg = threadIdx.x >> 8;
    const int b  = bg * 16 + bs;

    float a0 = 0.f, a1 = 0.f, a2 = 0.f;
    const int s0 = sg * 18;
    #pragma unroll
    for (int j = 0; j < 18; j += 3) {
        a0 += slab[(size_t)(s0 + j + 0) * CDB + (c * DV + d) * BATCH + b];
        a1 += slab[(size_t)(s0 + j + 1) * CDB + (c * DV + d) * BATCH + b];
        a2 += slab[(size_t)(s0 + j + 2) * CDB + (c * DV + d) * BATCH + b];
    }
    part[sg][d][bs] = (a0 + a1) + a2;
    __syncthreads();
    if (sg == 0)
        part[0][d][bs] = (part[0][d][bs] + part[1][d][bs])
                       + (part[2][d][bs] + part[3][d][bs]);
    __syncthreads();
    if (sg == 0) {
        float s = part[0][d][bs];
        float sq = 0.f;
        #pragma unroll
        for (int k = 0; k < DV; ++k) {
            float v = part[0][k][bs];
            sq = fmaf(v, v, sq);
        }
        // scale = sq/(1+sq)/sqrt(sq+EPS), EPS = 1e-7 (matches reference)
        float scale = sq / ((1.0f + sq) * sqrtf(sq + 1e-7f));
        float val = scale * s;
        if (LAST)
            outp[((size_t)b * NC + c) * DV + d] = val;   // out[b][c][d]
        else
            outp[(c * DV + d) * BATCH + b] = val;        // vT[c][d][b]
    }
}

// ---------------------------------------------------------------------------
extern "C" void kernel_launch(void* const* d_in, const int* in_sizes, int n_in,
                              void* d_out, int out_size, void* d_ws, size_t ws_size,
                              hipStream_t stream)
{
    const float* x    = (const float*)d_in[0];   // [256,1152,8]
    const float* W    = (const float*)d_in[1];   // [1152,10,16,8]
    const float* bias = (const float*)d_in[2];   // [1152,10]
    float* out = (float*)d_out;                  // [256,10,16]

    float* ws   = (float*)d_ws;
    float* slab = ws;                                  // 2,949,120 f
    float* cw_g = slab + (size_t)NSLAB * CDB;          // 2,949,120 f
    float* vT1  = cw_g + (size_t)IC * NC * BATCH;      //    40,960 f
    float* vT2  = vT1 + NC * DV * BATCH;               //    40,960 f
    float* xT   = vT2 + NC * DV * BATCH;               // 2,359,296 f
    float* cw1  = xT + (size_t)IC * BATCH * EDIM;      //    11,520 f
    // total ws use: ~33.3 MB (< 35.5 MB proven)

    dim3 gT(IC / 16, BATCH / 16);  // 72 x 16 transpose blocks
    dim3 gB(NSLAB, NC, 2);         // 1440 blocks
    dim3 gS(NC, 16);               // 160 blocks (1024 threads each)

    // one-time x transpose + cw1 precompute
    caps_xT<<<gT, 256, 0, stream>>>(x, bias, xT, cw1);
    // iter 1
    caps_wsum<1><<<gB, 256, 0, stream>>>(xT, W, cw1, cw_g, slab);
    caps_squash<0><<<gS, 1024, 0, stream>>>(slab, vT1);
    // iter 2
    caps_cw<2><<<IC, 256, 0, stream>>>(xT, W, bias, vT1, vT1, cw_g);
    caps_wsum<0><<<gB, 256, 0, stream>>>(xT, W, cw1, cw_g, slab);
    caps_squash<0><<<gS, 1024, 0, stream>>>(slab, vT2);
    // iter 3
    caps_cw<3><<<IC, 256, 0, stream>>>(xT, W, bias, vT1, vT2, cw_g);
    caps_wsum<0><<<gB, 256, 0, stream>>>(xT, W, cw1, cw_g, slab);
    caps_squash<1><<<gS, 1024, 0, stream>>>(slab, out);
}